// Round 21
// baseline (72.762 us; speedup 1.0000x reference)
//
#include <hip/hip_runtime.h>
#include <math.h>

// VectorQuantizer via MFMA. r21 = banked best-of: r14's argmin VERBATIM
// (12 structural probes r12-r20 failed to beat its ~32us: occupancy x3,
// staging, L1, coalescing, prefetch, barriers, MFMA->VALU distance,
// phase-batching, i8-K64 — all neutral-to-regressive; pipes serialize in
// lockstep and no source-level lever de-phased them) + r15's fused
// scatter+hist (deletes hist dispatch + 256KB partials round-trip) +
// direct-counts ppl. Key-packed argmin: A=bf16(-2x), C-init=cc+3.5,
// dpos in (3,4) (C-S bound) -> key=(asuint<<10)|code order-preserving,
// v_min_u32, exact first-index ties. absmax canary: 0.001934052.
// C/D: col=lane&15, row=(lane>>4)*4+reg (m89-verified).

#define NROWS (32 * 64 * 64)   // 131072
#define KCODES 1024
#define DIM 64

typedef __attribute__((ext_vector_type(8))) short bf16x8;
typedef __attribute__((ext_vector_type(4))) float f32x4;

__device__ __forceinline__ unsigned short f2bf(float f) {
    unsigned int u = __float_as_uint(f);
    return (unsigned short)((u + 0x7FFFu + ((u >> 16) & 1u)) >> 16);  // RNE
}

// ---- kernel 1: pack codebook into B-fragment order + biased norms ----
__global__ __launch_bounds__(256) void vq_prep_kernel(const float* __restrict__ cb,
                                                      float* __restrict__ cc35,
                                                      unsigned short* __restrict__ bfrag,
                                                      unsigned int* __restrict__ counts) {
    int slot = blockIdx.x * 256 + threadIdx.x;     // 0..8191
    int lane = slot & 63;
    int th   = slot >> 6;                          // tile*2 + khalf
    int tile = th >> 1, khalf = th & 1;
    int code = tile * 16 + (lane & 15);
    int k0   = khalf * 32 + (lane >> 4) * 8;
    const float* src = cb + code * DIM + k0;
    unsigned int w0 = (unsigned)f2bf(src[0]) | ((unsigned)f2bf(src[1]) << 16);
    unsigned int w1 = (unsigned)f2bf(src[2]) | ((unsigned)f2bf(src[3]) << 16);
    unsigned int w2 = (unsigned)f2bf(src[4]) | ((unsigned)f2bf(src[5]) << 16);
    unsigned int w3 = (unsigned)f2bf(src[6]) | ((unsigned)f2bf(src[7]) << 16);
    uint4 w; w.x = w0; w.y = w1; w.z = w2; w.w = w3;
    ((uint4*)bfrag)[slot] = w;

    if (slot < KCODES) {                           // norms + 3.5 bias; zero hist
        counts[slot] = 0u;
        const float* c = cb + slot * DIM;
        float a0 = 0.f, a1 = 0.f, a2 = 0.f, a3 = 0.f;
        #pragma unroll
        for (int i = 0; i < DIM; i += 4) {
            a0 = fmaf(c[i + 0], c[i + 0], a0);
            a1 = fmaf(c[i + 1], c[i + 1], a1);
            a2 = fmaf(c[i + 2], c[i + 2], a2);
            a3 = fmaf(c[i + 3], c[i + 3], a3);
        }
        cc35[slot] = ((a0 + a1) + (a2 + a3)) + 3.5f;
    }
}

// ---- kernel A: MFMA argmin with key packing (r14 VERBATIM) ----
// Block = 256 threads (4 waves), wave owns 4 strips of 16 rows = 64 rows,
// block = 256 rows, grid 512. LDS: 2 x 16KB B-tiles (dbuf) + 4KB cc35.
__global__ __launch_bounds__(256, 4) void vq_argmin_kernel(const float* __restrict__ x,
                                                           const float* __restrict__ cc35,
                                                           const unsigned short* __restrict__ bfrag,
                                                           unsigned int* __restrict__ idx) {
    __shared__ char  sb[2][16384];
    __shared__ float scc[KCODES];

    int t    = threadIdx.x;
    int lane = t & 63;
    int w    = t >> 6;                 // wave 0..3
    int rl   = lane & 15;
    int g    = lane >> 4;
    int base = blockIdx.x * 256;
    int row0 = base + w * 64;

    // stage cc35 (4KB, one issue) and B tile 0 (16KB, 4 issues)
    __builtin_amdgcn_global_load_lds(
        (const __attribute__((address_space(1))) void*)(cc35 + t * 4),
        (__attribute__((address_space(3))) void*)&scc[t * 4], 16, 0, 0);
    {
        const char* bsrc = (const char*)bfrag;
        #pragma unroll
        for (int r = 0; r < 4; ++r)
            __builtin_amdgcn_global_load_lds(
                (const __attribute__((address_space(1))) void*)(bsrc + r * 4096 + t * 16),
                (__attribute__((address_space(3))) void*)&sb[0][r * 4096 + t * 16],
                16, 0, 0);
    }

    // A fragments: 4 strips, both K-halves, bf16(-2x) (exact x2 scaling)
    bf16x8 aH0[4], aH1[4];
    #pragma unroll
    for (int s = 0; s < 4; ++s) {
        int r = row0 + s * 16 + rl;
        int n = r >> 12, hw = r & 4095;
        const float* xp = x + ((size_t)n << 18) + hw;
        #pragma unroll
        for (int j = 0; j < 8; ++j) {
            aH0[s][j] = (short)f2bf(-2.0f * xp[(size_t)(g * 8 + j) << 12]);
            aH1[s][j] = (short)f2bf(-2.0f * xp[(size_t)(g * 8 + j + 32) << 12]);
        }
    }

    unsigned int kk[4][4];
    #pragma unroll
    for (int s = 0; s < 4; ++s)
        #pragma unroll
        for (int i = 0; i < 4; ++i) kk[s][i] = 0xFFFFFFFFu;

    __syncthreads();                   // staging drained

    int buf = 0;
    for (int t8 = 0; t8 < 8; ++t8) {
        if (t8 + 1 < 8) {              // prefetch next 16KB tile
            const char* gp = (const char*)bfrag + (t8 + 1) * 16384;
            #pragma unroll
            for (int r = 0; r < 4; ++r)
                __builtin_amdgcn_global_load_lds(
                    (const __attribute__((address_space(1))) void*)(gp + r * 4096 + t * 16),
                    (__attribute__((address_space(3))) void*)&sb[buf ^ 1][r * 4096 + t * 16],
                    16, 0, 0);
        }

        const bf16x8* lv = (const bf16x8*)sb[buf];
        #pragma unroll
        for (int nt = 0; nt < 8; ++nt) {
            bf16x8 b0 = lv[(nt * 2 + 0) * 64 + lane];
            bf16x8 b1 = lv[(nt * 2 + 1) * 64 + lane];
            unsigned int code = (unsigned)((t8 * 8 + nt) * 16 + rl);
            float ccv = scc[(t8 * 8 + nt) * 16 + rl];

            #pragma unroll
            for (int s = 0; s < 4; ++s) {
                f32x4 acc = {ccv, ccv, ccv, ccv};
                acc = __builtin_amdgcn_mfma_f32_16x16x32_bf16(aH0[s], b0, acc, 0, 0, 0);
                acc = __builtin_amdgcn_mfma_f32_16x16x32_bf16(aH1[s], b1, acc, 0, 0, 0);
                // acc = 3.5 + cc - 2*x.c in (3,4): order-preserving key pack
                #pragma unroll
                for (int i = 0; i < 4; ++i) {
                    unsigned int key = (__float_as_uint(acc[i]) << 10) | code;
                    kk[s][i] = min(kk[s][i], key);
                }
            }
        }
        __syncthreads();               // all waves done with buf; prefetch landed
        buf ^= 1;
    }

    // butterfly min over 16 code-columns (low bits = code: first-index ties)
    #pragma unroll
    for (int off = 1; off <= 8; off <<= 1) {
        #pragma unroll
        for (int s = 0; s < 4; ++s)
            #pragma unroll
            for (int i = 0; i < 4; ++i)
                kk[s][i] = min(kk[s][i], (unsigned int)__shfl_xor((int)kk[s][i], off, 64));
    }

    // write idx: group g holds rows 4g+i; lanes rl<4 emit (static selects)
    if (rl < 4) {
        #pragma unroll
        for (int s = 0; s < 4; ++s) {
            unsigned int kr = (rl == 0) ? kk[s][0] : (rl == 1) ? kk[s][1]
                            : (rl == 2) ? kk[s][2] : kk[s][3];
            idx[row0 + s * 16 + 4 * g + rl] = kr & 1023u;
        }
    }
}

// ---- kernel B: gather q + coalesced out + fused histogram (r15-proven) ----
__global__ __launch_bounds__(256, 4) void vq_scatter_kernel(const unsigned int* __restrict__ idx,
                                                            const float* __restrict__ cb,
                                                            float* __restrict__ out,
                                                            unsigned int* __restrict__ counts) {
    __shared__ float tile[128 * 65];
    __shared__ unsigned int sidx[128];

    int t = threadIdx.x;
    int base = blockIdx.x * 128;
    int n = base >> 12, hw0 = base & 4095;

    if (t < 128) {
        unsigned int v = idx[base + t];
        sidx[t] = v;
        atomicAdd(&counts[v], 1u);     // fused histogram (131K atomics total)
    }
    __syncthreads();

    {
        int lr = t >> 1, h = t & 1;
        const float4* q = (const float4*)(cb + (size_t)sidx[lr] * DIM + h * 32);
        float4 q0 = q[0], q1 = q[1], q2 = q[2], q3 = q[3];
        float4 q4 = q[4], q5 = q[5], q6 = q[6], q7 = q[7];
        float qv[32] = {q0.x, q0.y, q0.z, q0.w, q1.x, q1.y, q1.z, q1.w,
                        q2.x, q2.y, q2.z, q2.w, q3.x, q3.y, q3.z, q3.w,
                        q4.x, q4.y, q4.z, q4.w, q5.x, q5.y, q5.z, q5.w,
                        q6.x, q6.y, q6.z, q6.w, q7.x, q7.y, q7.z, q7.w};
        float* srow = &tile[lr * 65 + h * 32];
        #pragma unroll
        for (int m = 0; m < 32; ++m) srow[m] = qv[m];
    }
    __syncthreads();

    {
        int half = t >> 7, lr = t & 127;
        float* orow = out + ((size_t)n << 18) + hw0 + lr;
        #pragma unroll
        for (int m = 0; m < 32; ++m) {
            int c = half * 32 + m;
            orow[(size_t)c << 12] = tile[lr * 65 + c];   // quantized == q
        }
    }
}

// ---- kernel C: perplexity from histogram ----
__global__ __launch_bounds__(1024) void vq_ppl_kernel(const unsigned int* __restrict__ counts,
                                                      float* __restrict__ out) {
    __shared__ float red[16];
    int k = threadIdx.x;
    float p = (float)counts[k] / (float)NROWS;
    float v = p * logf(p + 1e-10f);
    #pragma unroll
    for (int off = 32; off > 0; off >>= 1) v += __shfl_down(v, off, 64);
    int wave = k >> 6;
    int lane = k & 63;
    if (lane == 0) red[wave] = v;
    __syncthreads();
    if (k == 0) {
        float sum = 0.f;
        #pragma unroll
        for (int w = 0; w < 16; w++) sum += red[w];
        float ppl = expf(-sum);
        out[8388608] = 0.0f;   // loss (eval branch)
        out[8388609] = ppl;    // perplexity
    }
}

extern "C" void kernel_launch(void* const* d_in, const int* in_sizes, int n_in,
                              void* d_out, int out_size, void* d_ws, size_t ws_size,
                              hipStream_t stream) {
    const float* x  = (const float*)d_in[0];
    const float* cb = (const float*)d_in[1];
    float* out = (float*)d_out;

    float*          cc35   = (float*)d_ws;                            // 4 KB @ 0
    unsigned short* bfrag  = (unsigned short*)((char*)d_ws + 4096);   // 128 KB
    unsigned int*   idx    = (unsigned int*)((char*)d_ws + 135168);   // 512 KB
    unsigned int*   counts = (unsigned int*)((char*)d_ws + 659456);   // 4 KB

    vq_prep_kernel<<<32, 256, 0, stream>>>(cb, cc35, bfrag, counts);
    vq_argmin_kernel<<<NROWS / 256, 256, 0, stream>>>(x, cc35, bfrag, idx);
    vq_scatter_kernel<<<NROWS / 128, 256, 0, stream>>>(idx, cb, out, counts);
    vq_ppl_kernel<<<1, 1024, 0, stream>>>(counts, out);
}

// Round 22
// 54.020 us; speedup vs baseline: 1.3469x; 1.3469x over previous
//
#include <hip/hip_runtime.h>
#include <math.h>

// VectorQuantizer via MFMA. r22 = exact r14 restoration (53.9us champion).
// r21's lesson: fusing the histogram as a global-atomic burst into scatter
// cost +19us (131K atomics -> 4KB counts at block start, ~2048/line
// serialized at L2); r14's LDS-hist + partials tail is the right structure
// (atomic-free). Argmin: 12 structural probes (r12-r21) all neutral-to-
// regressive vs this form. Key-packed argmin: A=bf16(-2x), C-init=cc+3.5,
// dpos in (3,4) (C-S bound) -> key=(asuint<<10)|code order-preserving,
// v_min_u32, exact first-index ties. absmax canary: 0.001934052.
// C/D: col=lane&15, row=(lane>>4)*4+reg (m89-verified).

#define NROWS (32 * 64 * 64)   // 131072
#define KCODES 1024
#define DIM 64
#define HIST_BLOCKS 64

typedef __attribute__((ext_vector_type(8))) short bf16x8;
typedef __attribute__((ext_vector_type(4))) float f32x4;

__device__ __forceinline__ unsigned short f2bf(float f) {
    unsigned int u = __float_as_uint(f);
    return (unsigned short)((u + 0x7FFFu + ((u >> 16) & 1u)) >> 16);  // RNE
}

// ---- kernel 1: pack codebook into B-fragment order + biased norms ----
__global__ __launch_bounds__(256) void vq_prep_kernel(const float* __restrict__ cb,
                                                      float* __restrict__ cc35,
                                                      unsigned short* __restrict__ bfrag) {
    int slot = blockIdx.x * 256 + threadIdx.x;     // 0..8191
    int lane = slot & 63;
    int th   = slot >> 6;                          // tile*2 + khalf
    int tile = th >> 1, khalf = th & 1;
    int code = tile * 16 + (lane & 15);
    int k0   = khalf * 32 + (lane >> 4) * 8;
    const float* src = cb + code * DIM + k0;
    unsigned int w0 = (unsigned)f2bf(src[0]) | ((unsigned)f2bf(src[1]) << 16);
    unsigned int w1 = (unsigned)f2bf(src[2]) | ((unsigned)f2bf(src[3]) << 16);
    unsigned int w2 = (unsigned)f2bf(src[4]) | ((unsigned)f2bf(src[5]) << 16);
    unsigned int w3 = (unsigned)f2bf(src[6]) | ((unsigned)f2bf(src[7]) << 16);
    uint4 w; w.x = w0; w.y = w1; w.z = w2; w.w = w3;
    ((uint4*)bfrag)[slot] = w;

    if (slot < KCODES) {                           // fp32 norms + 3.5 bias
        const float* c = cb + slot * DIM;
        float a0 = 0.f, a1 = 0.f, a2 = 0.f, a3 = 0.f;
        #pragma unroll
        for (int i = 0; i < DIM; i += 4) {
            a0 = fmaf(c[i + 0], c[i + 0], a0);
            a1 = fmaf(c[i + 1], c[i + 1], a1);
            a2 = fmaf(c[i + 2], c[i + 2], a2);
            a3 = fmaf(c[i + 3], c[i + 3], a3);
        }
        cc35[slot] = ((a0 + a1) + (a2 + a3)) + 3.5f;
    }
}

// ---- kernel A: MFMA argmin with key packing (r14 VERBATIM) ----
// Block = 256 threads (4 waves), wave owns 4 strips of 16 rows = 64 rows,
// block = 256 rows, grid 512. LDS: 2 x 16KB B-tiles (dbuf) + 4KB cc35.
__global__ __launch_bounds__(256, 4) void vq_argmin_kernel(const float* __restrict__ x,
                                                           const float* __restrict__ cc35,
                                                           const unsigned short* __restrict__ bfrag,
                                                           unsigned int* __restrict__ idx) {
    __shared__ char  sb[2][16384];
    __shared__ float scc[KCODES];

    int t    = threadIdx.x;
    int lane = t & 63;
    int w    = t >> 6;                 // wave 0..3
    int rl   = lane & 15;
    int g    = lane >> 4;
    int base = blockIdx.x * 256;
    int row0 = base + w * 64;

    // stage cc35 (4KB, one issue) and B tile 0 (16KB, 4 issues)
    __builtin_amdgcn_global_load_lds(
        (const __attribute__((address_space(1))) void*)(cc35 + t * 4),
        (__attribute__((address_space(3))) void*)&scc[t * 4], 16, 0, 0);
    {
        const char* bsrc = (const char*)bfrag;
        #pragma unroll
        for (int r = 0; r < 4; ++r)
            __builtin_amdgcn_global_load_lds(
                (const __attribute__((address_space(1))) void*)(bsrc + r * 4096 + t * 16),
                (__attribute__((address_space(3))) void*)&sb[0][r * 4096 + t * 16],
                16, 0, 0);
    }

    // A fragments: 4 strips, both K-halves, bf16(-2x) (exact x2 scaling)
    bf16x8 aH0[4], aH1[4];
    #pragma unroll
    for (int s = 0; s < 4; ++s) {
        int r = row0 + s * 16 + rl;
        int n = r >> 12, hw = r & 4095;
        const float* xp = x + ((size_t)n << 18) + hw;
        #pragma unroll
        for (int j = 0; j < 8; ++j) {
            aH0[s][j] = (short)f2bf(-2.0f * xp[(size_t)(g * 8 + j) << 12]);
            aH1[s][j] = (short)f2bf(-2.0f * xp[(size_t)(g * 8 + j + 32) << 12]);
        }
    }

    unsigned int kk[4][4];
    #pragma unroll
    for (int s = 0; s < 4; ++s)
        #pragma unroll
        for (int i = 0; i < 4; ++i) kk[s][i] = 0xFFFFFFFFu;

    __syncthreads();                   // staging drained

    int buf = 0;
    for (int t8 = 0; t8 < 8; ++t8) {
        if (t8 + 1 < 8) {              // prefetch next 16KB tile
            const char* gp = (const char*)bfrag + (t8 + 1) * 16384;
            #pragma unroll
            for (int r = 0; r < 4; ++r)
                __builtin_amdgcn_global_load_lds(
                    (const __attribute__((address_space(1))) void*)(gp + r * 4096 + t * 16),
                    (__attribute__((address_space(3))) void*)&sb[buf ^ 1][r * 4096 + t * 16],
                    16, 0, 0);
        }

        const bf16x8* lv = (const bf16x8*)sb[buf];
        #pragma unroll
        for (int nt = 0; nt < 8; ++nt) {
            bf16x8 b0 = lv[(nt * 2 + 0) * 64 + lane];
            bf16x8 b1 = lv[(nt * 2 + 1) * 64 + lane];
            unsigned int code = (unsigned)((t8 * 8 + nt) * 16 + rl);
            float ccv = scc[(t8 * 8 + nt) * 16 + rl];

            #pragma unroll
            for (int s = 0; s < 4; ++s) {
                f32x4 acc = {ccv, ccv, ccv, ccv};
                acc = __builtin_amdgcn_mfma_f32_16x16x32_bf16(aH0[s], b0, acc, 0, 0, 0);
                acc = __builtin_amdgcn_mfma_f32_16x16x32_bf16(aH1[s], b1, acc, 0, 0, 0);
                // acc = 3.5 + cc - 2*x.c in (3,4): order-preserving key pack
                #pragma unroll
                for (int i = 0; i < 4; ++i) {
                    unsigned int key = (__float_as_uint(acc[i]) << 10) | code;
                    kk[s][i] = min(kk[s][i], key);
                }
            }
        }
        __syncthreads();               // all waves done with buf; prefetch landed
        buf ^= 1;
    }

    // butterfly min over 16 code-columns (low bits = code: first-index ties)
    #pragma unroll
    for (int off = 1; off <= 8; off <<= 1) {
        #pragma unroll
        for (int s = 0; s < 4; ++s)
            #pragma unroll
            for (int i = 0; i < 4; ++i)
                kk[s][i] = min(kk[s][i], (unsigned int)__shfl_xor((int)kk[s][i], off, 64));
    }

    // write idx: group g holds rows 4g+i; lanes rl<4 emit (static selects)
    if (rl < 4) {
        #pragma unroll
        for (int s = 0; s < 4; ++s) {
            unsigned int kr = (rl == 0) ? kk[s][0] : (rl == 1) ? kk[s][1]
                            : (rl == 2) ? kk[s][2] : kk[s][3];
            idx[row0 + s * 16 + 4 * g + rl] = kr & 1023u;
        }
    }
}

// ---- kernel B: gather q via LDS transpose, coalesced out (atomic-free) ----
__global__ __launch_bounds__(256, 4) void vq_scatter_kernel(const unsigned int* __restrict__ idx,
                                                            const float* __restrict__ cb,
                                                            float* __restrict__ out) {
    __shared__ float tile[128 * 65];
    __shared__ unsigned int sidx[128];

    int t = threadIdx.x;
    int base = blockIdx.x * 128;
    int n = base >> 12, hw0 = base & 4095;

    if (t < 128) sidx[t] = idx[base + t];
    __syncthreads();

    {
        int lr = t >> 1, h = t & 1;
        const float4* q = (const float4*)(cb + (size_t)sidx[lr] * DIM + h * 32);
        float4 q0 = q[0], q1 = q[1], q2 = q[2], q3 = q[3];
        float4 q4 = q[4], q5 = q[5], q6 = q[6], q7 = q[7];
        float qv[32] = {q0.x, q0.y, q0.z, q0.w, q1.x, q1.y, q1.z, q1.w,
                        q2.x, q2.y, q2.z, q2.w, q3.x, q3.y, q3.z, q3.w,
                        q4.x, q4.y, q4.z, q4.w, q5.x, q5.y, q5.z, q5.w,
                        q6.x, q6.y, q6.z, q6.w, q7.x, q7.y, q7.z, q7.w};
        float* srow = &tile[lr * 65 + h * 32];
        #pragma unroll
        for (int m = 0; m < 32; ++m) srow[m] = qv[m];
    }
    __syncthreads();

    {
        int half = t >> 7, lr = t & 127;
        float* orow = out + ((size_t)n << 18) + hw0 + lr;
        #pragma unroll
        for (int m = 0; m < 32; ++m) {
            int c = half * 32 + m;
            orow[(size_t)c << 12] = tile[lr * 65 + c];   // quantized == q
        }
    }
}

// ---- kernel C: histogram, zero global atomics (LDS hist -> partials) ----
__global__ __launch_bounds__(256) void vq_hist_kernel(const unsigned int* __restrict__ idx,
                                                      unsigned int* __restrict__ partials) {
    __shared__ unsigned int lh[KCODES];
    int t = threadIdx.x;
    #pragma unroll
    for (int j = t; j < KCODES; j += 256) lh[j] = 0u;
    __syncthreads();
    int base = blockIdx.x * (NROWS / HIST_BLOCKS);
    #pragma unroll
    for (int i = t; i < NROWS / HIST_BLOCKS; i += 256)
        atomicAdd(&lh[idx[base + i]], 1u);
    __syncthreads();
    #pragma unroll
    for (int j = t; j < KCODES; j += 256)
        partials[blockIdx.x * KCODES + j] = lh[j];
}

// ---- kernel D: perplexity from partial histograms ----
__global__ __launch_bounds__(1024) void vq_ppl_kernel(const unsigned int* __restrict__ partials,
                                                      float* __restrict__ out) {
    __shared__ float red[16];
    int k = threadIdx.x;
    unsigned int cnt = 0u;
    #pragma unroll
    for (int b = 0; b < HIST_BLOCKS; ++b) cnt += partials[b * KCODES + k];
    float p = (float)cnt / (float)NROWS;
    float v = p * logf(p + 1e-10f);
    #pragma unroll
    for (int off = 32; off > 0; off >>= 1) v += __shfl_down(v, off, 64);
    int wave = k >> 6;
    int lane = k & 63;
    if (lane == 0) red[wave] = v;
    __syncthreads();
    if (k == 0) {
        float sum = 0.f;
        #pragma unroll
        for (int w = 0; w < 16; w++) sum += red[w];
        float ppl = expf(-sum);
        out[8388608] = 0.0f;   // loss (eval branch)
        out[8388609] = ppl;    // perplexity
    }
}

extern "C" void kernel_launch(void* const* d_in, const int* in_sizes, int n_in,
                              void* d_out, int out_size, void* d_ws, size_t ws_size,
                              hipStream_t stream) {
    const float* x  = (const float*)d_in[0];
    const float* cb = (const float*)d_in[1];
    float* out = (float*)d_out;

    float*          cc35     = (float*)d_ws;                            // 4 KB @ 0
    unsigned short* bfrag    = (unsigned short*)((char*)d_ws + 4096);   // 128 KB
    unsigned int*   idx      = (unsigned int*)((char*)d_ws + 135168);   // 512 KB
    unsigned int*   partials = (unsigned int*)((char*)d_ws + 659456);   // 256 KB

    vq_prep_kernel<<<32, 256, 0, stream>>>(cb, cc35, bfrag);
    vq_argmin_kernel<<<NROWS / 256, 256, 0, stream>>>(x, cc35, bfrag, idx);
    vq_scatter_kernel<<<NROWS / 128, 256, 0, stream>>>(idx, cb, out);
    vq_hist_kernel<<<HIST_BLOCKS, 256, 0, stream>>>(idx, partials);
    vq_ppl_kernel<<<1, 1024, 0, stream>>>(partials, out);
}